// Round 9
// baseline (122.494 us; speedup 1.0000x reference)
//
#include <hip/hip_runtime.h>

namespace {

constexpr int L     = 128;
constexpr int NANG  = 120;
constexpr int CHUNK = 24;                 // angles per aftab refill (5 chunks)
constexpr size_t H16_BYTES = (size_t)2 * NANG * L * L * 2;   // 7,864,320

typedef __fp16 f16x2 __attribute__((ext_vector_type(2)));
typedef __fp16 f16x4 __attribute__((ext_vector_type(4)));
typedef float  f32x4 __attribute__((ext_vector_type(4)));

// Prepass: image f32 -> f16 (rtz, identical bits to the f32 path's cvt of B).
__global__ __launch_bounds__(256) void cvt16_kernel(const float* __restrict__ in,
                                                    unsigned* __restrict__ out) {
    const int i = ((int)blockIdx.x * 256 + (int)threadIdx.x) * 4;
    const float4 v = *reinterpret_cast<const float4*>(in + i);
    f16x2 a = __builtin_amdgcn_cvt_pkrtz(v.x, v.y);
    f16x2 b = __builtin_amdgcn_cvt_pkrtz(v.z, v.w);
    uint2 st;
    st.x = *reinterpret_cast<unsigned*>(&a);
    st.y = *reinterpret_cast<unsigned*>(&b);
    *reinterpret_cast<uint2*>(out + i / 2) = st;
}

// R9: OCCUPANCY round. R8 counters (VALUBusy 38, MfmaUtil 24, FETCH 15MB,
// Occupancy 36%) = latency-bound at 4 waves/SIMD; the fix is 2 blocks/CU.
//  * Grid 512 = 256 Morton tiles x 2 z-halves (consecutive -> same XCD);
//    1024 thr; __launch_bounds__(1024, 8) -> 8 waves/SIMD, 32 waves/CU.
//  * LDS ~50 KiB: aftab holds CHUNK=24 angles of FINAL MFMA-ready u64 frags
//    (48 KiB), refilled 5x. Refill computes geometry ONCE per (a,p) then
//    scatters 4 quad entries (R8 recomputed geometry per entry = 4x waste).
//  * Wave = (zq2, b, aset parity, mhalf): mhalf splits the 4 M-tiles 2/2 ->
//    acc 16 VGPR, per-angle 2 ds_read_b64 + 4 dword loads + 4 perm + 4 MFMA.
//    B-loads duplicated across mhalf siblings are L1 hits (same lines).
//  * No per-3-angle pacing barrier: chunk refill barriers (every 12 angles)
//    bound drift; 2 independent blocks/CU fill each other's stalls.
// Kept: Morton/XCD map, exact 12-row window, quad3 row-dup (A-frag 0 there),
// f16 prepass, reduction through retired aftab LDS, coalesced float2 stores.
template <bool F16>
__global__ __launch_bounds__(1024, 8) void bp_kernel(
    const void* __restrict__ imgv,     // f16: [2,120,128,128] half; f32: float
    const float* __restrict__ angles,  // [120] deg
    float* __restrict__ out)           // [2,128,128,128] f32
{
    constexpr unsigned SLICE = F16 ? 32768u : 65536u;
    constexpr unsigned ROWB  = F16 ? 256u  : 512u;
    constexpr int      RSH   = F16 ? 8 : 9;          // row -> byte shift

    __shared__ unsigned long long aftab[CHUNK * 4 * 64];  // 48 KiB [ia][m][lane]
    __shared__ float2   acs[NANG];        // 960 B
    __shared__ unsigned arloB[NANG];      // 480 B, (window first row) << RSH
    __shared__ alignas(16) float nrmtab[64];

    const int tid = threadIdx.x;
    // XCD chunking (512 = 8 x 64): both z-halves of a tile are consecutive n
    // -> same XCD. Morton tile decode (16x16 tiles of 8x8 points).
    const int bid  = (int)blockIdx.x;
    const int n    = ((bid & 7) << 6) | (bid >> 3);
    const int zhf  = n & 1;
    const int tt   = n >> 1;
    int xt = 0, yt = 0;
#pragma unroll
    for (int i = 0; i < 4; ++i) {
        xt |= ((tt >> (2 * i)) & 1) << i;
        yt |= ((tt >> (2 * i + 1)) & 1) << i;
    }
    const int xb = xt * 8, yb = yt * 8;
    const float cx = (L - 1) * 0.5f;

    // ---- Phase 0: rotation params + 12-row window floor (exact, no margin) --
    if (tid < NANG) {
        const float phi = -angles[tid] * 0.017453292519943295f;
        float s, c;
        sincosf(phi, &s, &c);
        const float X0 = (float)xb - cx,  X1 = (float)(xb + 7) - cx;
        const float Y0 = (float)yb - cx,  Y1 = (float)(yb + 7) - cx;
        const float a00 = -s * X0 + c * Y0 + cx;
        const float a01 = -s * X0 + c * Y1 + cx;
        const float a10 = -s * X1 + c * Y0 + cx;
        const float a11 = -s * X1 + c * Y1 + cx;
        const float symin = fminf(fminf(a00, a01), fminf(a10, a11));
        acs[tid]   = make_float2(c, s);
        arloB[tid] = (unsigned)min(max((int)floorf(symin), 0), 116) << RSH;
    }
    if (tid < 64) nrmtab[tid] = 0.f;
    __syncthreads();

    const int wave  = tid >> 6;
    const int lane  = tid & 63;
    const int quad  = lane >> 4;
    const int lhalf = lane & 15;
    const int zq2   = wave & 1;            // 32-z chunk within the z-half
    const int b     = (wave >> 1) & 1;
    const int aset  = (wave >> 2) & 1;     // angle parity within chunk
    const int mhalf = wave >> 3;           // M-tiles {0,1} or {2,3}
    const char* __restrict__ imgc = (const char*)imgv;

    const unsigned bbase_s = __builtin_amdgcn_readfirstlane((unsigned)(b * NANG) * SLICE);
    // quad's 4-row subgroup (quad3 dups quad0: its A-frag is provably 0) + z
    const unsigned voffc = (unsigned)((quad == 3) ? 0 : quad) * 4u * ROWB
        + (unsigned)(zhf * 64 + zq2 * 32 + 2 * lhalf) * (F16 ? 2u : 4u);

    // ---- Chunk fill: geometry ONCE per (a,p), scatter 4 quad entries ----
    auto fill_chunk = [&](int c) {
        for (int e = tid; e < CHUNK * 64; e += 1024) {
            const int p  = e & 63;
            const int ia = e >> 6;
            const int a  = c * CHUNK + ia;
            const float2 cs = acs[a];
            const int rlo = (int)(arloB[a] >> RSH);
            const float X = (float)(xb + (p >> 3)) - cx;
            const float Y = (float)(yb + (p & 7)) - cx;
            const float sx =  cs.x * X + cs.y * Y + cx;
            const float sy = -cs.y * X + cs.x * Y + cx;
            const float x0f = floorf(sx), y0f = floorf(sy);
            const float wx = sx - x0f,    wy = sy - y0f;
            const int x0 = (int)x0f, y0 = (int)y0f;
            const float mx0 = (x0 >= 0  && x0 <  L)     ? 1.f : 0.f;
            const float mx1 = (x0 >= -1 && x0 <= L - 2) ? 1.f : 0.f;
            const float my0 = (y0 >= 0  && y0 <  L)     ? 1.f : 0.f;
            const float my1 = (y0 >= -1 && y0 <= L - 2) ? 1.f : 0.f;
            const float A   = (1.f - wx) * mx0 + wx * mx1;
            float w0f = (1.f - wy) * my0 * A;
            float w1f = wy * my1 * A;
            const int y0c = min(max(y0, 0), L - 1);
            const int y1c = min(max(y0 + 1, 0), L - 1);
            const int s0  = min(max(y0c - rlo, 0), 11);
            const int s1  = min(max(y1c - rlo, 0), 11);
            if (s0 == s1) { w0f += w1f; w1f = 0.f; }   // clamp collision fold
            f16x2 wh = __builtin_amdgcn_cvt_pkrtz(w0f, w1f);
            const unsigned wbits = *reinterpret_cast<unsigned*>(&wh);
            const unsigned t  = (unsigned)s0 & 3u;
            const int      q0 = s0 >> 2;                  // 0..2
            const unsigned long long W = (unsigned long long)wbits << (t * 16u);
            const unsigned long long spill =
                (t == 3u) ? (unsigned long long)(wbits >> 16) : 0ull;
            const int eb = ia * 256 + (p >> 4) * 64 + (p & 15);
#pragma unroll
            for (int qd = 0; qd < 4; ++qd)
                aftab[eb + qd * 16] =
                    (qd == q0) ? W : ((qd == q0 + 1) ? spill : 0ull);
            atomicAdd(&nrmtab[p], w0f + w1f);   // once per (a,p)
        }
    };

    f32x4 acc[2][2] = {};   // [m within mhalf][z parity]

    auto issue = [&](unsigned long long* af, unsigned* r, float2* rf,
                     int i, int c) {
        const int ia = aset + 2 * i;           // interleaved walk within chunk
        const int a  = c * CHUNK + ia;
#pragma unroll
        for (int m = 0; m < 2; ++m)            // MFMA-ready frags (this mhalf)
            af[m] = aftab[ia * 256 + (mhalf * 2 + m) * 64 + lane];
        const unsigned rlB = __builtin_amdgcn_readfirstlane(arloB[a]);
        const char* pa = imgc + (bbase_s + (unsigned)a * SLICE + rlB);
        if constexpr (F16) {
#pragma unroll
            for (int j = 0; j < 4; ++j)        // row sub_j, imm j*256
                r[j] = *(const unsigned*)(pa + (voffc + (unsigned)j * ROWB));
        } else {
#pragma unroll
            for (int j = 0; j < 4; ++j)
                rf[j] = *(const float2*)(pa + (voffc + (unsigned)j * ROWB));
        }
    };
    auto compute = [&](const unsigned long long* af, const unsigned* r,
                       const float2* rf) {
        union { unsigned u[2]; f16x4 v; } B0, B1;
        if constexpr (F16) {
            B0.u[0] = __builtin_amdgcn_perm(r[1], r[0], 0x05040100u);
            B0.u[1] = __builtin_amdgcn_perm(r[3], r[2], 0x05040100u);
            B1.u[0] = __builtin_amdgcn_perm(r[1], r[0], 0x07060302u);
            B1.u[1] = __builtin_amdgcn_perm(r[3], r[2], 0x07060302u);
        } else {
            const f16x2 h0a = __builtin_amdgcn_cvt_pkrtz(rf[0].x, rf[1].x);
            const f16x2 h0b = __builtin_amdgcn_cvt_pkrtz(rf[2].x, rf[3].x);
            const f16x2 h1a = __builtin_amdgcn_cvt_pkrtz(rf[0].y, rf[1].y);
            const f16x2 h1b = __builtin_amdgcn_cvt_pkrtz(rf[2].y, rf[3].y);
            B0.v = f16x4{h0a.x, h0a.y, h0b.x, h0b.y};
            B1.v = f16x4{h1a.x, h1a.y, h1b.x, h1b.y};
        }
#pragma unroll
        for (int m = 0; m < 2; ++m) {
            union { unsigned long long u; f16x4 v; } afu; afu.u = af[m];
            acc[m][0] = __builtin_amdgcn_mfma_f32_16x16x16f16(afu.v, B0.v, acc[m][0], 0, 0, 0);
            acc[m][1] = __builtin_amdgcn_mfma_f32_16x16x16f16(afu.v, B1.v, acc[m][1], 0, 0, 0);
        }
    };

    // ---- 5 chunks: refill aftab, then 3-buffer pipeline over 12 angles ----
    unsigned long long aA[2], aB[2], aC[2];
    unsigned rA[4], rB[4], rC[4];
    float2   fA[4], fB[4], fC[4];

    for (int c = 0; c < 5; ++c) {
        fill_chunk(c);
        __syncthreads();                       // aftab ready
        issue(aA, rA, fA, 0, c);
        issue(aB, rB, fB, 1, c);
        for (int i = 0; i < 12; i += 3) {
            if (i + 2 < 12) issue(aC, rC, fC, i + 2, c);
            compute(aA, rA, fA);
            if (i + 3 < 12) issue(aA, rA, fA, i + 3, c);
            compute(aB, rB, fB);
            if (i + 4 < 12) issue(aB, rB, fB, i + 4, c);
            compute(aC, rC, fC);
        }
        __syncthreads();                       // aftab reusable (refill/reduce)
    }

    // ---- aset-pair reduction (aset1 -> aset0) in retired aftab LDS ----
    float4* red = reinterpret_cast<float4*>(aftab);   // need 32 KiB of 48
    const int pr = (zq2 << 2) | (b << 1) | mhalf;     // 0..7
    if (aset == 1) {
#pragma unroll
        for (int m = 0; m < 2; ++m)
#pragma unroll
            for (int zg = 0; zg < 2; ++zg)
                red[(pr * 4 + m * 2 + zg) * 64 + lane] =
                    make_float4(acc[m][zg][0], acc[m][zg][1],
                                acc[m][zg][2], acc[m][zg][3]);
    }
    __syncthreads();
    if (aset == 0) {
#pragma unroll
        for (int m = 0; m < 2; ++m)
#pragma unroll
            for (int zg = 0; zg < 2; ++zg) {
                const float4 o = red[(pr * 4 + m * 2 + zg) * 64 + lane];
                acc[m][zg][0] += o.x; acc[m][zg][1] += o.y;
                acc[m][zg][2] += o.z; acc[m][zg][3] += o.w;
            }
        // ---- Epilogue: p = (mhalf*2+m)*16 + quad*4 + r;
        //      z = zhf*64 + zq2*32 + 2*lhalf + zg -> float2 store ----
        const int zb = zhf * 64 + zq2 * 32 + 2 * lhalf;
#pragma unroll
        for (int m = 0; m < 2; ++m) {
            const int mm = mhalf * 2 + m;
            const float4 nrm4 = *(const float4*)&nrmtab[mm * 16 + quad * 4];
            const float iv[4] = { 1.f / (nrm4.x + 1e-11f), 1.f / (nrm4.y + 1e-11f),
                                  1.f / (nrm4.z + 1e-11f), 1.f / (nrm4.w + 1e-11f) };
#pragma unroll
            for (int r = 0; r < 4; ++r) {
                const int p = mm * 16 + quad * 4 + r;
                const int x = xb + (p >> 3);
                const int y = yb + (p & 7);
                const float2 o = make_float2(acc[m][0][r] * iv[r],
                                             acc[m][1][r] * iv[r]);
                *reinterpret_cast<float2*>(
                    &out[(((size_t)(b * L + x)) * L + y) * L + zb]) = o;
            }
        }
    }
}

} // namespace

extern "C" void kernel_launch(void* const* d_in, const int* in_sizes, int n_in,
                              void* d_out, int out_size, void* d_ws, size_t ws_size,
                              hipStream_t stream) {
    const float* image  = (const float*)d_in[0];
    const float* angles = (const float*)d_in[1];
    float* out = (float*)d_out;
    (void)in_sizes; (void)n_in; (void)out_size;

    dim3 grid(512);   // 256 tiles x 2 z-halves = 2 blocks per CU
    if (d_ws != nullptr && ws_size >= H16_BYTES) {
        cvt16_kernel<<<dim3(3840), 256, 0, stream>>>(image, (unsigned*)d_ws);
        bp_kernel<true><<<grid, 1024, 0, stream>>>(d_ws, angles, out);
    } else {
        bp_kernel<false><<<grid, 1024, 0, stream>>>(image, angles, out);
    }
}

// Round 10
// 108.807 us; speedup vs baseline: 1.1258x; 1.1258x over previous
//
#include <hip/hip_runtime.h>

namespace {

constexpr int L     = 128;
constexpr int NANG  = 120;
constexpr size_t H16_BYTES = (size_t)2 * NANG * L * L * 2;   // 7,864,320

typedef __fp16 f16x2 __attribute__((ext_vector_type(2)));
typedef __fp16 f16x4 __attribute__((ext_vector_type(4)));
typedef float  f32x4 __attribute__((ext_vector_type(4)));

typedef const __attribute__((address_space(1))) unsigned GConstUint;
typedef __attribute__((address_space(3))) unsigned LdsUint;

// Prepass: image f32 -> f16 (rtz, identical bits to the f32 path's cvt of B).
__global__ __launch_bounds__(256) void cvt16_kernel(const float* __restrict__ in,
                                                    unsigned* __restrict__ out) {
    const int i = ((int)blockIdx.x * 256 + (int)threadIdx.x) * 4;
    const float4 v = *reinterpret_cast<const float4*>(in + i);
    f16x2 a = __builtin_amdgcn_cvt_pkrtz(v.x, v.y);
    f16x2 b = __builtin_amdgcn_cvt_pkrtz(v.z, v.w);
    uint2 st;
    st.x = *reinterpret_cast<unsigned*>(&a);
    st.y = *reinterpret_cast<unsigned*>(&b);
    *reinterpret_cast<uint2*>(out + i / 2) = st;
}

// R10 = R6 (best measured: bp ~43.7us) + ONE additive phase.
// R7's REPS=2 decomposition: warm main pass = 21.4us, cold pass ~= 42us ->
// ~20us of bp is FIRST-TOUCH L3 latency (cvt16's output homes in the writer
// XCD's L2, not the consumer's; FETCH_SIZE can't see L3->L2 traffic).
// Fix: fire-and-forget global_load_lds PREFETCH of the block's entire window
// stream (120 ang x 2 b x 3KB contiguous 12-row windows = 720 KB) into a 1KB
// dummy LDS buffer, issued right after phase0 in REVERSE-angle order (per-XCD
// union ~4.8MB slightly exceeds 4MiB L2; reverse issue keeps first-consumed
// angles most recent). Drains during phase1; the pre-loop __syncthreads is
// the vmcnt(0) sync point. No VGPR cost, no hazard (dummy dest), strictly
// additive -- worst case perf == R6.
// Everything else identical to R6: grid 256 (1 blk/CU), 1024 thr = 16 waves,
// 8x8 tile, both b, interleaved angle walk + s_barrier pacing, K=16 MFMA with
// exact 12-row window, quad3 row-dup, pre-shifted A-frags in wtab LDS,
// aset-pair reduction through retired wtab, coalesced float2 stores.
template <bool F16>
__global__ __launch_bounds__(1024, 4) void bp_kernel(
    const void* __restrict__ imgv,     // f16: [2,120,128,128] half; f32: float
    const float* __restrict__ angles,  // [120] deg
    float* __restrict__ out)           // [2,128,128,128] f32
{
    constexpr unsigned SLICE = F16 ? 32768u : 65536u;
    constexpr unsigned ROWB  = F16 ? 256u  : 512u;
    constexpr int      RSH   = F16 ? 8 : 9;          // row -> byte shift

    __shared__ uint4    wtab[NANG * 64];   // 120 KiB: [a][p]{Wlo,Whi,spill,q0}
    __shared__ float2   acs[NANG];
    __shared__ unsigned arloB[NANG];       // (window first row) << RSH
    __shared__ alignas(16) float nrmtab[64];
    __shared__ alignas(16) unsigned pfdummy[256];   // 1 KiB prefetch sink

    const int tid = threadIdx.x;
    // XCD chunking (256 = 8 x 32) + Morton tile decode (16x16 tiles of 8x8).
    const int bid = (int)blockIdx.x;
    const int n   = ((bid & 7) << 5) | (bid >> 3);
    int xt = 0, yt = 0;
#pragma unroll
    for (int i = 0; i < 4; ++i) {
        xt |= ((n >> (2 * i)) & 1) << i;
        yt |= ((n >> (2 * i + 1)) & 1) << i;
    }
    const int xb = xt * 8, yb = yt * 8;
    const float cx = (L - 1) * 0.5f;

    // ---- Phase 0: rotation params + 12-row window floor (exact, no margin) --
    if (tid < NANG) {
        const float phi = -angles[tid] * 0.017453292519943295f;
        float s, c;
        sincosf(phi, &s, &c);
        const float X0 = (float)xb - cx,  X1 = (float)(xb + 7) - cx;
        const float Y0 = (float)yb - cx,  Y1 = (float)(yb + 7) - cx;
        const float a00 = -s * X0 + c * Y0 + cx;
        const float a01 = -s * X0 + c * Y1 + cx;
        const float a10 = -s * X1 + c * Y0 + cx;
        const float a11 = -s * X1 + c * Y1 + cx;
        const float symin = fminf(fminf(a00, a01), fminf(a10, a11));
        acs[tid]   = make_float2(c, s);
        arloB[tid] = (unsigned)min(max((int)floorf(symin), 0), 116) << RSH;
    }
    if (tid < 64) nrmtab[tid] = 0.f;
    __syncthreads();

    const char* __restrict__ imgc = (const char*)imgv;

    // ---- Prefetch phase (F16 path): warm this XCD's L2 with the block's
    //      full window stream. Window (a,b) = ONE contiguous 3 KiB span
    //      (rows rlo..rlo+11). 240 windows x 3 insts / 16 waves = 45/wave.
    //      Reverse-angle order; results land in pfdummy (never read).
    if constexpr (F16) {
        const int wv = tid >> 6;
        const int ln = tid & 63;
#pragma unroll 1
        for (int t = 0; t < 15; ++t) {
            const int W  = wv + (t << 4);          // 0..239
            const int a  = 119 - (W >> 1);         // reverse-angle
            const int bb = W & 1;
            const unsigned rlB = __builtin_amdgcn_readfirstlane(arloB[a]);
            const char* base = imgc + ((unsigned)(bb * NANG + a) * SLICE + rlB);
#pragma unroll
            for (int k = 0; k < 3; ++k)
                __builtin_amdgcn_global_load_lds(
                    (GConstUint*)(base + (unsigned)(k * 1024 + ln * 16)),
                    (LdsUint*)&pfdummy[0], 16, 0, 0);
        }
    }

    // ---- Phase 1: per-(angle,point) pre-shifted A-fragments + norm sums
    //      (runs while the prefetch stream drains) ----
    float wsum = 0.f;
#pragma unroll
    for (int k = 0; k < 8; ++k) {
        const int e = tid + k * 1024;          // e = a*64 + p (p = tid&63 fixed)
        if (e < NANG * 64) {
            const int p = e & 63;
            const int a = e >> 6;
            const float2 cs = acs[a];
            const int rlo = (int)(arloB[a] >> RSH);
            const float X = (float)(xb + (p >> 3)) - cx;
            const float Y = (float)(yb + (p & 7)) - cx;
            const float sx =  cs.x * X + cs.y * Y + cx;
            const float sy = -cs.y * X + cs.x * Y + cx;
            const float x0f = floorf(sx), y0f = floorf(sy);
            const float wx = sx - x0f,    wy = sy - y0f;
            const int x0 = (int)x0f, y0 = (int)y0f;
            const float mx0 = (x0 >= 0  && x0 <  L)     ? 1.f : 0.f;
            const float mx1 = (x0 >= -1 && x0 <= L - 2) ? 1.f : 0.f;
            const float my0 = (y0 >= 0  && y0 <  L)     ? 1.f : 0.f;
            const float my1 = (y0 >= -1 && y0 <= L - 2) ? 1.f : 0.f;
            const float A   = (1.f - wx) * mx0 + wx * mx1;
            float w0f = (1.f - wy) * my0 * A;
            float w1f = wy * my1 * A;
            const int y0c = min(max(y0, 0), L - 1);
            const int y1c = min(max(y0 + 1, 0), L - 1);
            const int s0  = min(max(y0c - rlo, 0), 11);
            const int s1  = min(max(y1c - rlo, 0), 11);
            if (s0 == s1) { w0f += w1f; w1f = 0.f; }   // clamp collision fold
            f16x2 wh = __builtin_amdgcn_cvt_pkrtz(w0f, w1f);
            const unsigned wbits = *reinterpret_cast<unsigned*>(&wh);
            const unsigned t  = (unsigned)s0 & 3u;
            const unsigned q0 = (unsigned)s0 >> 2;        // 0..2
            const unsigned long long W = (unsigned long long)wbits << (t * 16u);
            const unsigned spill = (t == 3u) ? (wbits >> 16) : 0u;
            uint4 ent;
            ent.x = (unsigned)W;
            ent.y = (unsigned)(W >> 32);
            ent.z = spill;                                // goes to quad q0+1
            ent.w = q0;
            wtab[a * 64 + p] = ent;
            wsum += w0f + w1f;
        }
    }
    atomicAdd(&nrmtab[tid & 63], wsum);
    __syncthreads();   // drains vmcnt(0): prefetch stream complete, L2 warm

    const int wave  = tid >> 6;
    const int lane  = tid & 63;
    const int quad  = lane >> 4;
    const int lhalf = lane & 15;
    const int zq    = wave & 3;            // 32-z chunk
    const int b     = (wave >> 2) & 1;
    const int aset  = wave >> 3;           // angle parity (interleaved)

    const unsigned bbase_s = __builtin_amdgcn_readfirstlane((unsigned)(b * NANG) * SLICE);
    // per-lane constant offset: quad's 4-row subgroup (quad3 dups quad0) + z
    const unsigned voffc = (unsigned)((quad == 3) ? 0 : quad) * 4u * ROWB
                         + (unsigned)(zq * 32 + 2 * lhalf) * (F16 ? 2u : 4u);

    f32x4 acc[4][2] = {};   // [Mtile][z parity]

    auto issue = [&](uint4* e, unsigned* r, float2* rf, int i) {
        const int a = aset + 2 * i;            // INTERLEAVED angle walk
#pragma unroll
        for (int m = 0; m < 4; ++m)            // A-frag entries, imm m*256
            e[m] = wtab[a * 64 + m * 16 + lhalf];
        const unsigned rlB = __builtin_amdgcn_readfirstlane(arloB[a]);
        const char* pa = imgc + (bbase_s + (unsigned)a * SLICE + rlB);
        if constexpr (F16) {
#pragma unroll
            for (int j = 0; j < 4; ++j)        // row sub_j, imm j*256
                r[j] = *(const unsigned*)(pa + (voffc + (unsigned)j * ROWB));
        } else {
#pragma unroll
            for (int j = 0; j < 4; ++j)
                rf[j] = *(const float2*)(pa + (voffc + (unsigned)j * ROWB));
        }
    };
    auto compute = [&](const uint4* e, const unsigned* r, const float2* rf) {
        union { unsigned u[2]; f16x4 v; } B0, B1;
        if constexpr (F16) {
            B0.u[0] = __builtin_amdgcn_perm(r[1], r[0], 0x05040100u);
            B0.u[1] = __builtin_amdgcn_perm(r[3], r[2], 0x05040100u);
            B1.u[0] = __builtin_amdgcn_perm(r[1], r[0], 0x07060302u);
            B1.u[1] = __builtin_amdgcn_perm(r[3], r[2], 0x07060302u);
        } else {
            const f16x2 h0a = __builtin_amdgcn_cvt_pkrtz(rf[0].x, rf[1].x);
            const f16x2 h0b = __builtin_amdgcn_cvt_pkrtz(rf[2].x, rf[3].x);
            const f16x2 h1a = __builtin_amdgcn_cvt_pkrtz(rf[0].y, rf[1].y);
            const f16x2 h1b = __builtin_amdgcn_cvt_pkrtz(rf[2].y, rf[3].y);
            B0.v = f16x4{h0a.x, h0a.y, h0b.x, h0b.y};
            B1.v = f16x4{h1a.x, h1a.y, h1b.x, h1b.y};
        }
#pragma unroll
        for (int m = 0; m < 4; ++m) {
            const int q0 = (int)e[m].w;
            union { unsigned u[2]; f16x4 v; } af;
            af.u[0] = (quad == q0) ? e[m].x : ((quad == q0 + 1) ? e[m].z : 0u);
            af.u[1] = (quad == q0) ? e[m].y : 0u;
            acc[m][0] = __builtin_amdgcn_mfma_f32_16x16x16f16(af.v, B0.v, acc[m][0], 0, 0, 0);
            acc[m][1] = __builtin_amdgcn_mfma_f32_16x16x16f16(af.v, B1.v, acc[m][1], 0, 0, 0);
        }
    };

    // ---- Main loop: 3-buffer pipeline over this wave's 60 angles,
    //      barrier-paced per group (register-only state, uniform trips) ----
    uint4    eA[4], eB[4], eC[4];
    unsigned rA[4], rB[4], rC[4];
    float2   fA[4], fB[4], fC[4];

    issue(eA, rA, fA, 0);
    issue(eB, rB, fB, 1);

    for (int i = 0; i < 60; i += 3) {
        if (i + 2 < 60) issue(eC, rC, fC, i + 2);
        compute(eA, rA, fA);
        if (i + 3 < 60) issue(eA, rA, fA, i + 3);
        compute(eB, rB, fB);
        if (i + 4 < 60) issue(eB, rB, fB, i + 4);
        compute(eC, rC, fC);
        __builtin_amdgcn_s_barrier();          // pacing only
    }

    // ---- aset-pair reduction (aset1 -> aset0) in retired wtab LDS ----
    __syncthreads();                        // everyone done with wtab/arloB
    float4* red = reinterpret_cast<float4*>(wtab);   // 64 KiB of 120 KiB
    const int pr = wave & 7;                // pair id: (zq, b)
    if (aset == 1) {
#pragma unroll
        for (int m = 0; m < 4; ++m)
#pragma unroll
            for (int zg = 0; zg < 2; ++zg)
                red[(pr * 8 + m * 2 + zg) * 64 + lane] =
                    make_float4(acc[m][zg][0], acc[m][zg][1],
                                acc[m][zg][2], acc[m][zg][3]);
    }
    __syncthreads();
    if (aset == 0) {
#pragma unroll
        for (int m = 0; m < 4; ++m)
#pragma unroll
            for (int zg = 0; zg < 2; ++zg) {
                const float4 o = red[(pr * 8 + m * 2 + zg) * 64 + lane];
                acc[m][zg][0] += o.x; acc[m][zg][1] += o.y;
                acc[m][zg][2] += o.z; acc[m][zg][3] += o.w;
            }
        // ---- Epilogue: p = m*16 + quad*4 + r; z = zq*32 + 2*lhalf + zg ----
        const int zb = zq * 32 + 2 * lhalf;
#pragma unroll
        for (int m = 0; m < 4; ++m) {
            const float4 nrm4 = *(const float4*)&nrmtab[m * 16 + quad * 4];
            const float iv[4] = { 1.f / (nrm4.x + 1e-11f), 1.f / (nrm4.y + 1e-11f),
                                  1.f / (nrm4.z + 1e-11f), 1.f / (nrm4.w + 1e-11f) };
#pragma unroll
            for (int r = 0; r < 4; ++r) {
                const int p = m * 16 + quad * 4 + r;
                const int x = xb + (p >> 3);
                const int y = yb + (p & 7);
                const float2 o = make_float2(acc[m][0][r] * iv[r],
                                             acc[m][1][r] * iv[r]);
                *reinterpret_cast<float2*>(
                    &out[(((size_t)(b * L + x)) * L + y) * L + zb]) = o;
            }
        }
    }
}

} // namespace

extern "C" void kernel_launch(void* const* d_in, const int* in_sizes, int n_in,
                              void* d_out, int out_size, void* d_ws, size_t ws_size,
                              hipStream_t stream) {
    const float* image  = (const float*)d_in[0];
    const float* angles = (const float*)d_in[1];
    float* out = (float*)d_out;
    (void)in_sizes; (void)n_in; (void)out_size;

    dim3 grid(256);   // 16x16 tiles of 8x8 points, both b per block = 1 per CU
    if (d_ws != nullptr && ws_size >= H16_BYTES) {
        cvt16_kernel<<<dim3(3840), 256, 0, stream>>>(image, (unsigned*)d_ws);
        bp_kernel<true><<<grid, 1024, 0, stream>>>(d_ws, angles, out);
    } else {
        bp_kernel<false><<<grid, 1024, 0, stream>>>(image, angles, out);
    }
}